// Round 10
// baseline (67.146 us; speedup 1.0000x reference)
//
#include <hip/hip_runtime.h>
#include <hip/hip_bf16.h>

// PolymorphicSNN: reference collapses to
//   out[:, :256]     = heaviside(x @ W_lin.T + b_lin - 1.0)
//   out[:, 256:8448] = 0    (spk_mode == 0 identically since reg_out in {0,1})
//
// Ladder: 74 (f64 mono) -> 69 (f32+recheck) -> 59.9 (WT coalesced, interleaved
// fill, regular stores, 8 waves/CU). Still 4.8 TB/s effective vs 6.9 fill rate.
// This round: 16 waves/CU (1024 blocks x 8 rows, launch_bounds(256,4)) and
// W prefetch depth 2 (decouple the pre-FMA vmcnt wait from store drain:
// in-order vmcnt completion queues a 1-iter-old load behind our own fill
// stores; 2 iterations ~ 300 cyc covers L2 latency).

#define SNN_B 8192
#define SNN_N 256
#define SNN_P 32
#define SNN_ROW (SNN_N * (SNN_P + 1))   // 8448 floats per output row
#define BLK_ROWS 8                      // batch rows per block (2 per wave)

// ---- Pre-pass: W_T[k][n] = W[n][k] (256x256) ----
__global__ __launch_bounds__(256) void w_transpose_kernel(
    const float* __restrict__ W, float* __restrict__ WT)
{
    const int o = blockIdx.x * 256 + threadIdx.x;   // coalesced write
    const int k = o >> 8, n = o & 255;
    WT[o] = W[n * SNN_N + k];
}

// ---- Main: GEMM + spikes + interleaved zero-fill ----
__global__ __launch_bounds__(256, 4) void polysnn_main_kernel(
    const float* __restrict__ x,      // [B, N]
    const float* __restrict__ W,      // [N, N] original (borderline recheck only)
    const float* __restrict__ WT,     // [N, N] transposed: WT[k][n]
    const float* __restrict__ bias,   // [N]
    float* __restrict__ out)          // [B, 8448]
{
    __shared__ float xs[BLK_ROWS][SNN_N];

    const int tid  = threadIdx.x;
    const int lane = tid & 63;
    const int wave = tid >> 6;
    const int row0 = blockIdx.x * BLK_ROWS;

    // Stage 8 x-rows (8 KB): 512 float4, 2 per thread.
    {
        const float4* x4  = reinterpret_cast<const float4*>(x + (size_t)row0 * SNN_N);
        float4*       xsw = reinterpret_cast<float4*>(&xs[0][0]);
        xsw[tid]       = x4[tid];
        xsw[tid + 256] = x4[tid + 256];
    }
    __syncthreads();

    // Wave handles rows grow0, grow0+1; lane owns cols 4*lane..4*lane+3.
    const int grow0 = row0 + wave * 2;
    const float4* wt4 = reinterpret_cast<const float4*>(WT);   // [k][64 float4]
    const float4* xs4 = reinterpret_cast<const float4*>(&xs[0][0]);
    const int xbase = wave * 2 * 64;   // float4 index of this wave's first row

    float acc[2][4];
#pragma unroll
    for (int r = 0; r < 2; ++r)
#pragma unroll
        for (int c = 0; c < 4; ++c) acc[r][c] = 0.0f;

    // Prefetch depth 2: named register sets A (even iters) and B (odd iters).
    float4 wa0 = wt4[(0 * 4 + 0) * 64 + lane];
    float4 wa1 = wt4[(0 * 4 + 1) * 64 + lane];
    float4 wa2 = wt4[(0 * 4 + 2) * 64 + lane];
    float4 wa3 = wt4[(0 * 4 + 3) * 64 + lane];
    float4 wb0 = wt4[(1 * 4 + 0) * 64 + lane];
    float4 wb1 = wt4[(1 * 4 + 1) * 64 + lane];
    float4 wb2 = wt4[(1 * 4 + 2) * 64 + lane];
    float4 wb3 = wt4[(1 * 4 + 3) * 64 + lane];
    float4 xc0 = xs4[xbase + 0 * 64 + 0];
    float4 xc1 = xs4[xbase + 1 * 64 + 0];

    float* const wfill = out + (size_t)grow0 * SNN_ROW;  // wave's first out row
    const float4 z = make_float4(0.f, 0.f, 0.f, 0.f);

#define SNN_FMA_BLOCK(W0, W1, W2, W3)                                   \
    do {                                                                \
        acc[0][0] = fmaf(xc0.x, W0.x, acc[0][0]);                       \
        acc[0][1] = fmaf(xc0.x, W0.y, acc[0][1]);                       \
        acc[0][2] = fmaf(xc0.x, W0.z, acc[0][2]);                       \
        acc[0][3] = fmaf(xc0.x, W0.w, acc[0][3]);                       \
        acc[0][0] = fmaf(xc0.y, W1.x, acc[0][0]);                       \
        acc[0][1] = fmaf(xc0.y, W1.y, acc[0][1]);                       \
        acc[0][2] = fmaf(xc0.y, W1.z, acc[0][2]);                       \
        acc[0][3] = fmaf(xc0.y, W1.w, acc[0][3]);                       \
        acc[0][0] = fmaf(xc0.z, W2.x, acc[0][0]);                       \
        acc[0][1] = fmaf(xc0.z, W2.y, acc[0][1]);                       \
        acc[0][2] = fmaf(xc0.z, W2.z, acc[0][2]);                       \
        acc[0][3] = fmaf(xc0.z, W2.w, acc[0][3]);                       \
        acc[0][0] = fmaf(xc0.w, W3.x, acc[0][0]);                       \
        acc[0][1] = fmaf(xc0.w, W3.y, acc[0][1]);                       \
        acc[0][2] = fmaf(xc0.w, W3.z, acc[0][2]);                       \
        acc[0][3] = fmaf(xc0.w, W3.w, acc[0][3]);                       \
        acc[1][0] = fmaf(xc1.x, W0.x, acc[1][0]);                       \
        acc[1][1] = fmaf(xc1.x, W0.y, acc[1][1]);                       \
        acc[1][2] = fmaf(xc1.x, W0.z, acc[1][2]);                       \
        acc[1][3] = fmaf(xc1.x, W0.w, acc[1][3]);                       \
        acc[1][0] = fmaf(xc1.y, W1.x, acc[1][0]);                       \
        acc[1][1] = fmaf(xc1.y, W1.y, acc[1][1]);                       \
        acc[1][2] = fmaf(xc1.y, W1.z, acc[1][2]);                       \
        acc[1][3] = fmaf(xc1.y, W1.w, acc[1][3]);                       \
        acc[1][0] = fmaf(xc1.z, W2.x, acc[1][0]);                       \
        acc[1][1] = fmaf(xc1.z, W2.y, acc[1][1]);                       \
        acc[1][2] = fmaf(xc1.z, W2.z, acc[1][2]);                       \
        acc[1][3] = fmaf(xc1.z, W2.w, acc[1][3]);                       \
        acc[1][0] = fmaf(xc1.w, W3.x, acc[1][0]);                       \
        acc[1][1] = fmaf(xc1.w, W3.y, acc[1][1]);                       \
        acc[1][2] = fmaf(xc1.w, W3.z, acc[1][2]);                       \
        acc[1][3] = fmaf(xc1.w, W3.w, acc[1][3]);                       \
    } while (0)

    for (int i = 0; i < 64; i += 2) {
        // ---- even sub-iter: consume A, prefetch iter i+2 into A ----
        {
            const int ip = (i + 2) & 63;
            float4 t0 = wt4[(ip * 4 + 0) * 64 + lane];
            float4 t1 = wt4[(ip * 4 + 1) * 64 + lane];
            float4 t2 = wt4[(ip * 4 + 2) * 64 + lane];
            float4 t3 = wt4[(ip * 4 + 3) * 64 + lane];
            const int ixp = (i + 1) & 63;
            float4 xn0 = xs4[xbase + 0 * 64 + ixp];
            float4 xn1 = xs4[xbase + 1 * 64 + ixp];
            const int fidx = (i << 6) + lane;            // 1 fill store / iter
            *reinterpret_cast<float4*>(
                wfill + (fidx >> 11) * SNN_ROW + SNN_N + ((fidx & 2047) << 2)) = z;
            SNN_FMA_BLOCK(wa0, wa1, wa2, wa3);
            wa0 = t0; wa1 = t1; wa2 = t2; wa3 = t3;
            xc0 = xn0; xc1 = xn1;
        }
        // ---- odd sub-iter: consume B, prefetch iter i+3 into B ----
        {
            const int ip = (i + 3) & 63;
            float4 t0 = wt4[(ip * 4 + 0) * 64 + lane];
            float4 t1 = wt4[(ip * 4 + 1) * 64 + lane];
            float4 t2 = wt4[(ip * 4 + 2) * 64 + lane];
            float4 t3 = wt4[(ip * 4 + 3) * 64 + lane];
            const int ixp = (i + 2) & 63;
            float4 xn0 = xs4[xbase + 0 * 64 + ixp];
            float4 xn1 = xs4[xbase + 1 * 64 + ixp];
            const int fidx = ((i + 1) << 6) + lane;
            *reinterpret_cast<float4*>(
                wfill + (fidx >> 11) * SNN_ROW + SNN_N + ((fidx & 2047) << 2)) = z;
            SNN_FMA_BLOCK(wb0, wb1, wb2, wb3);
            wb0 = t0; wb1 = t1; wb2 = t2; wb3 = t3;
            xc0 = xn0; xc1 = xn1;
        }
    }
#undef SNN_FMA_BLOCK

    // ---- epilogue: bias, threshold, rare f64 recheck, coalesced spike store ----
    const float4 bb = reinterpret_cast<const float4*>(bias)[lane];
#pragma unroll
    for (int r = 0; r < 2; ++r) {
        float h[4] = {acc[r][0] + bb.x, acc[r][1] + bb.y,
                      acc[r][2] + bb.z, acc[r][3] + bb.w};
        float s[4];
#pragma unroll
        for (int c = 0; c < 4; ++c) {
            if (__builtin_expect(fabsf(h[c] - 1.0f) < 1e-3f, 0)) {
                // Borderline (f32 accum error <= ~6e-5 << 1e-3): f64 recheck.
                const int n = 4 * lane + c;
                double a = (double)bias[n];
                const float* wr = W + (size_t)n * SNN_N;
                for (int k = 0; k < SNN_N; ++k)
                    a += (double)wr[k] * (double)xs[wave * 2 + r][k];
                s[c] = (a > 1.0) ? 1.0f : 0.0f;
            } else {
                s[c] = (h[c] > 1.0f) ? 1.0f : 0.0f;
            }
        }
        *reinterpret_cast<float4*>(out + (size_t)(grow0 + r) * SNN_ROW + (lane << 2))
            = make_float4(s[0], s[1], s[2], s[3]);
    }
}

// ---- Fallback (ws too small): round-2 monolithic kernel (69 us, absmax 0) ----
__global__ __launch_bounds__(256) void polysnn_mono_kernel(
    const float* __restrict__ x, const float* __restrict__ W,
    const float* __restrict__ bias, float* __restrict__ out)
{
    __shared__ float xs[8][SNN_N];
    const int tid = threadIdx.x;
    const int row0 = blockIdx.x * 8;
    {
        const float4* x4  = reinterpret_cast<const float4*>(x + (size_t)row0 * SNN_N);
        float4*       xsw = reinterpret_cast<float4*>(&xs[0][0]);
        xsw[tid] = x4[tid]; xsw[tid + 256] = x4[tid + 256];
    }
    __syncthreads();
    const float4 zz = make_float4(0.f, 0.f, 0.f, 0.f);
#pragma unroll
    for (int r = 0; r < 8; ++r) {
        float4* o4 = reinterpret_cast<float4*>(out + (size_t)(row0 + r) * SNN_ROW + SNN_N);
#pragma unroll
        for (int i = 0; i < 8; ++i) o4[tid + i * 256] = zz;
    }
    const int n = tid;
    float acc[8];
#pragma unroll
    for (int r = 0; r < 8; ++r) acc[r] = 0.0f;
    const float4* w4  = reinterpret_cast<const float4*>(W + (size_t)n * SNN_N);
    const float4* xs4 = reinterpret_cast<const float4*>(&xs[0][0]);
#pragma unroll 4
    for (int k4 = 0; k4 < SNN_N / 4; ++k4) {
        const float4 w = w4[k4];
#pragma unroll
        for (int r = 0; r < 8; ++r) {
            const float4 xr = xs4[r * 64 + k4];
            acc[r] = fmaf(w.x, xr.x, acc[r]); acc[r] = fmaf(w.y, xr.y, acc[r]);
            acc[r] = fmaf(w.z, xr.z, acc[r]); acc[r] = fmaf(w.w, xr.w, acc[r]);
        }
    }
    const float bn = bias[n];
#pragma unroll
    for (int r = 0; r < 8; ++r) {
        const float h = acc[r] + bn;
        float spike;
        if (__builtin_expect(fabsf(h - 1.0f) < 1e-3f, 0)) {
            double a = (double)bn;
            const float* wr = W + (size_t)n * SNN_N;
            for (int k = 0; k < SNN_N; ++k) a += (double)wr[k] * (double)xs[r][k];
            spike = (a > 1.0) ? 1.0f : 0.0f;
        } else spike = (h > 1.0f) ? 1.0f : 0.0f;
        out[(size_t)(row0 + r) * SNN_ROW + n] = spike;
    }
}

extern "C" void kernel_launch(void* const* d_in, const int* in_sizes, int n_in,
                              void* d_out, int out_size, void* d_ws, size_t ws_size,
                              hipStream_t stream) {
    const float* x     = (const float*)d_in[0];
    const float* W_lin = (const float*)d_in[1];
    const float* b_lin = (const float*)d_in[2];
    // d_in[3] (W_sel) and d_in[4] (b_sel) are dead: spk_mode == 0 identically.
    float* out = (float*)d_out;

    if (ws_size >= (size_t)SNN_N * SNN_N * sizeof(float)) {
        float* WT = (float*)d_ws;
        w_transpose_kernel<<<256, 256, 0, stream>>>(W_lin, WT);
        polysnn_main_kernel<<<SNN_B / BLK_ROWS, 256, 0, stream>>>(x, W_lin, WT, b_lin, out);
    } else {
        polysnn_mono_kernel<<<SNN_B / 8, 256, 0, stream>>>(x, W_lin, b_lin, out);
    }
}

// Round 11
// 65.871 us; speedup vs baseline: 1.0194x; 1.0194x over previous
//
#include <hip/hip_runtime.h>
#include <hip/hip_bf16.h>

// PolymorphicSNN: reference collapses to
//   out[:, :256]     = heaviside(x @ W_lin.T + b_lin - 1.0)
//   out[:, 256:8448] = 0    (spk_mode == 0 identically since reg_out in {0,1})
//
// Ladder: 74 -> 69 -> 59.9 (R9: WT+interleaved fill, 4 rows/wave, regular
// stores) ; R10 (2 rows/wave) regressed to 67.1 -> W L2 traffic scales as
// 1/rows-per-wave. R8 (8 rows/wave) was 72.7 but NT-store-bound (3.9 TB/s).
// This round: R8's 8-rows/wave structure + REGULAR stores.
//   - 256 blocks (1/CU, no tail), 4 waves, wave = 8 rows x 256 cols
//   - WT L2 read traffic: 256 MB (half of R9)
//   - 4 fill stores per k-iter interleaved behind prefetched W loads

#define SNN_B 8192
#define SNN_N 256
#define SNN_P 32
#define SNN_ROW (SNN_N * (SNN_P + 1))   // 8448 floats per output row
#define BLK_ROWS 32                     // batch rows per block (8 per wave)

// ---- Pre-pass: W_T[k][n] = W[n][k] (256x256) ----
__global__ __launch_bounds__(256) void w_transpose_kernel(
    const float* __restrict__ W, float* __restrict__ WT)
{
    const int o = blockIdx.x * 256 + threadIdx.x;   // coalesced write
    const int k = o >> 8, n = o & 255;
    WT[o] = W[n * SNN_N + k];
}

// ---- Main: GEMM + spikes + interleaved zero-fill (regular stores) ----
__global__ __launch_bounds__(256) void polysnn_main_kernel(
    const float* __restrict__ x,      // [B, N]
    const float* __restrict__ W,      // [N, N] original (borderline recheck only)
    const float* __restrict__ WT,     // [N, N] transposed: WT[k][n]
    const float* __restrict__ bias,   // [N]
    float* __restrict__ out)          // [B, 8448]
{
    __shared__ float xs[BLK_ROWS][SNN_N];

    const int tid  = threadIdx.x;
    const int lane = tid & 63;
    const int wave = tid >> 6;
    const int row0 = blockIdx.x * BLK_ROWS;

    // Stage 32 x-rows (32 KB, contiguous): 8192 floats = 2048 float4.
    {
        const float4* x4  = reinterpret_cast<const float4*>(x + (size_t)row0 * SNN_N);
        float4*       xsw = reinterpret_cast<float4*>(&xs[0][0]);
#pragma unroll
        for (int i = 0; i < 8; ++i) xsw[tid + i * 256] = x4[tid + i * 256];
    }
    __syncthreads();

    // Wave handles rows row0+8*wave .. +7; lane owns cols 4*lane..4*lane+3.
    const int grow0 = row0 + wave * 8;
    const float4* wt4 = reinterpret_cast<const float4*>(WT);   // [k][64 float4]
    const float4* xs4 = reinterpret_cast<const float4*>(&xs[0][0]);
    const int xbase = wave * 8 * 64;   // float4 index of this wave's first row

    float acc[8][4];
#pragma unroll
    for (int r = 0; r < 8; ++r)
#pragma unroll
        for (int c = 0; c < 4; ++c) acc[r][c] = 0.0f;

    // Prefetch iter 0: W_T rows k=0..3, this lane's 16 B (coalesced).
    float4 wcur0 = wt4[0 * 64 + lane];
    float4 wcur1 = wt4[1 * 64 + lane];
    float4 wcur2 = wt4[2 * 64 + lane];
    float4 wcur3 = wt4[3 * 64 + lane];
    float4 xcur[8];
#pragma unroll
    for (int r = 0; r < 8; ++r) xcur[r] = xs4[xbase + r * 64 + 0];

    float* const wfill = out + (size_t)grow0 * SNN_ROW;  // wave's first out row
    const float4 z = make_float4(0.f, 0.f, 0.f, 0.f);

    for (int i = 0; i < 64; ++i) {
        // ---- prefetch next iteration (wrap at end; redundant last loads) ----
        const int ip = (i + 1) & 63;
        float4 wnx0 = wt4[(ip * 4 + 0) * 64 + lane];
        float4 wnx1 = wt4[(ip * 4 + 1) * 64 + lane];
        float4 wnx2 = wt4[(ip * 4 + 2) * 64 + lane];
        float4 wnx3 = wt4[(ip * 4 + 3) * 64 + lane];
        float4 xnxt[8];
#pragma unroll
        for (int r = 0; r < 8; ++r) xnxt[r] = xs4[xbase + r * 64 + ip];

        // ---- interleaved zero-fill: 4 REGULAR stores (behind the loads) ----
        // Wave fill region = 8 rows x 8192 floats; fidx = (i*4+j)*64 + lane.
#pragma unroll
        for (int j = 0; j < 4; ++j) {
            const int fidx = ((i * 4 + j) << 6) + lane;
            const int rl   = fidx >> 11;          // 2048 float4 per row
            const int c4   = fidx & 2047;
            *reinterpret_cast<float4*>(wfill + rl * SNN_ROW + SNN_N + (c4 << 2)) = z;
        }

        // ---- compute iter i: 128 FMAs ----
#pragma unroll
        for (int r = 0; r < 8; ++r) {
            const float4 xr = xcur[r];
            acc[r][0] = fmaf(xr.x, wcur0.x, acc[r][0]);
            acc[r][1] = fmaf(xr.x, wcur0.y, acc[r][1]);
            acc[r][2] = fmaf(xr.x, wcur0.z, acc[r][2]);
            acc[r][3] = fmaf(xr.x, wcur0.w, acc[r][3]);
            acc[r][0] = fmaf(xr.y, wcur1.x, acc[r][0]);
            acc[r][1] = fmaf(xr.y, wcur1.y, acc[r][1]);
            acc[r][2] = fmaf(xr.y, wcur1.z, acc[r][2]);
            acc[r][3] = fmaf(xr.y, wcur1.w, acc[r][3]);
            acc[r][0] = fmaf(xr.z, wcur2.x, acc[r][0]);
            acc[r][1] = fmaf(xr.z, wcur2.y, acc[r][1]);
            acc[r][2] = fmaf(xr.z, wcur2.z, acc[r][2]);
            acc[r][3] = fmaf(xr.z, wcur2.w, acc[r][3]);
            acc[r][0] = fmaf(xr.w, wcur3.x, acc[r][0]);
            acc[r][1] = fmaf(xr.w, wcur3.y, acc[r][1]);
            acc[r][2] = fmaf(xr.w, wcur3.z, acc[r][2]);
            acc[r][3] = fmaf(xr.w, wcur3.w, acc[r][3]);
        }

        wcur0 = wnx0; wcur1 = wnx1; wcur2 = wnx2; wcur3 = wnx3;
#pragma unroll
        for (int r = 0; r < 8; ++r) xcur[r] = xnxt[r];
    }

    // ---- epilogue: bias, threshold, rare f64 recheck, coalesced spike store ----
    const float4 bb = reinterpret_cast<const float4*>(bias)[lane];
#pragma unroll
    for (int r = 0; r < 8; ++r) {
        float h[4] = {acc[r][0] + bb.x, acc[r][1] + bb.y,
                      acc[r][2] + bb.z, acc[r][3] + bb.w};
        float s[4];
#pragma unroll
        for (int c = 0; c < 4; ++c) {
            if (__builtin_expect(fabsf(h[c] - 1.0f) < 1e-3f, 0)) {
                // Borderline (f32 accum error <= ~6e-5 << 1e-3): f64 recheck.
                const int n = 4 * lane + c;
                double a = (double)bias[n];
                const float* wr = W + (size_t)n * SNN_N;
                for (int k = 0; k < SNN_N; ++k)
                    a += (double)wr[k] * (double)xs[wave * 8 + r][k];
                s[c] = (a > 1.0) ? 1.0f : 0.0f;
            } else {
                s[c] = (h[c] > 1.0f) ? 1.0f : 0.0f;
            }
        }
        *reinterpret_cast<float4*>(out + (size_t)(grow0 + r) * SNN_ROW + (lane << 2))
            = make_float4(s[0], s[1], s[2], s[3]);
    }
}

// ---- Fallback (ws too small): round-2 monolithic kernel (69 us, absmax 0) ----
__global__ __launch_bounds__(256) void polysnn_mono_kernel(
    const float* __restrict__ x, const float* __restrict__ W,
    const float* __restrict__ bias, float* __restrict__ out)
{
    __shared__ float xs[8][SNN_N];
    const int tid = threadIdx.x;
    const int row0 = blockIdx.x * 8;
    {
        const float4* x4  = reinterpret_cast<const float4*>(x + (size_t)row0 * SNN_N);
        float4*       xsw = reinterpret_cast<float4*>(&xs[0][0]);
        xsw[tid] = x4[tid]; xsw[tid + 256] = x4[tid + 256];
    }
    __syncthreads();
    const float4 zz = make_float4(0.f, 0.f, 0.f, 0.f);
#pragma unroll
    for (int r = 0; r < 8; ++r) {
        float4* o4 = reinterpret_cast<float4*>(out + (size_t)(row0 + r) * SNN_ROW + SNN_N);
#pragma unroll
        for (int i = 0; i < 8; ++i) o4[tid + i * 256] = zz;
    }
    const int n = tid;
    float acc[8];
#pragma unroll
    for (int r = 0; r < 8; ++r) acc[r] = 0.0f;
    const float4* w4  = reinterpret_cast<const float4*>(W + (size_t)n * SNN_N);
    const float4* xs4 = reinterpret_cast<const float4*>(&xs[0][0]);
#pragma unroll 4
    for (int k4 = 0; k4 < SNN_N / 4; ++k4) {
        const float4 w = w4[k4];
#pragma unroll
        for (int r = 0; r < 8; ++r) {
            const float4 xr = xs4[r * 64 + k4];
            acc[r] = fmaf(w.x, xr.x, acc[r]); acc[r] = fmaf(w.y, xr.y, acc[r]);
            acc[r] = fmaf(w.z, xr.z, acc[r]); acc[r] = fmaf(w.w, xr.w, acc[r]);
        }
    }
    const float bn = bias[n];
#pragma unroll
    for (int r = 0; r < 8; ++r) {
        const float h = acc[r] + bn;
        float spike;
        if (__builtin_expect(fabsf(h - 1.0f) < 1e-3f, 0)) {
            double a = (double)bn;
            const float* wr = W + (size_t)n * SNN_N;
            for (int k = 0; k < SNN_N; ++k) a += (double)wr[k] * (double)xs[r][k];
            spike = (a > 1.0) ? 1.0f : 0.0f;
        } else spike = (h > 1.0f) ? 1.0f : 0.0f;
        out[(size_t)(row0 + r) * SNN_ROW + n] = spike;
    }
}

extern "C" void kernel_launch(void* const* d_in, const int* in_sizes, int n_in,
                              void* d_out, int out_size, void* d_ws, size_t ws_size,
                              hipStream_t stream) {
    const float* x     = (const float*)d_in[0];
    const float* W_lin = (const float*)d_in[1];
    const float* b_lin = (const float*)d_in[2];
    // d_in[3] (W_sel) and d_in[4] (b_sel) are dead: spk_mode == 0 identically.
    float* out = (float*)d_out;

    if (ws_size >= (size_t)SNN_N * SNN_N * sizeof(float)) {
        float* WT = (float*)d_ws;
        w_transpose_kernel<<<256, 256, 0, stream>>>(W_lin, WT);
        polysnn_main_kernel<<<SNN_B / BLK_ROWS, 256, 0, stream>>>(x, W_lin, WT, b_lin, out);
    } else {
        polysnn_mono_kernel<<<SNN_B / 8, 256, 0, stream>>>(x, W_lin, b_lin, out);
    }
}

// Round 12
// 64.337 us; speedup vs baseline: 1.0437x; 1.0238x over previous
//
#include <hip/hip_runtime.h>
#include <hip/hip_bf16.h>

// PolymorphicSNN: reference collapses to
//   out[:, :256]     = heaviside(x @ W_lin.T + b_lin - 1.0)
//   out[:, 256:8448] = 0    (spk_mode == 0 identically since reg_out in {0,1})
//
// Ladder: 74 -> 69 -> 59.9 (R9: WT + per-iter interleaved fill, 8 waves/CU).
// Occupancy sweep says 8 waves/CU is optimal; interleaved-per-iter store
// stream still only reaches 4.8 TB/s vs rocclr fill's 6.9 (pure bursts).
// This round: WAVE-PHASE STAGGER. Each wave does both roles sequentially,
// in opposite order by parity: {GEMM -> fill} vs {fill -> GEMM}. Parity
// (wave ^ (blockIdx>>8)) puts one fill-wave + one gemm-wave on each SIMD
// (co-resident blocks b and b+256). Fill = pure 128-store burst (rocclr-
// like); GEMM waves' vmcnt queue is load-only. Work is identical per wave
// and per CU -> no imbalance (the R3/R5/R6 trap).

#define SNN_B 8192
#define SNN_N 256
#define SNN_P 32
#define SNN_ROW (SNN_N * (SNN_P + 1))   // 8448 floats per output row
#define BLK_ROWS 16                     // batch rows per block (4 per wave)

// ---- Pre-pass: W_T[k][n] = W[n][k] (256x256) ----
__global__ __launch_bounds__(256) void w_transpose_kernel(
    const float* __restrict__ W, float* __restrict__ WT)
{
    const int o = blockIdx.x * 256 + threadIdx.x;   // coalesced write
    const int k = o >> 8, n = o & 255;
    WT[o] = W[n * SNN_N + k];
}

// ---- Main: phase-staggered fill + GEMM ----
__global__ __launch_bounds__(256, 2) void polysnn_main_kernel(
    const float* __restrict__ x,      // [B, N]
    const float* __restrict__ W,      // [N, N] original (borderline recheck only)
    const float* __restrict__ WT,     // [N, N] transposed: WT[k][n]
    const float* __restrict__ bias,   // [N]
    float* __restrict__ out)          // [B, 8448]
{
    __shared__ float xs[BLK_ROWS][SNN_N];

    const int tid  = threadIdx.x;
    const int lane = tid & 63;
    const int wave = tid >> 6;
    const int row0 = blockIdx.x * BLK_ROWS;

    // Stage 16 x-rows (16 KB): 1024 float4, 4 per thread.
    {
        const float4* x4  = reinterpret_cast<const float4*>(x + (size_t)row0 * SNN_N);
        float4*       xsw = reinterpret_cast<float4*>(&xs[0][0]);
#pragma unroll
        for (int i = 0; i < 4; ++i) xsw[tid + i * 256] = x4[tid + i * 256];
    }
    __syncthreads();

    const int grow0 = row0 + wave * 4;   // wave owns 4 output rows
    const int phase = (wave ^ (blockIdx.x >> 8)) & 1;

    // ---------- FILL: pure store burst, 4 rows x 8192 floats = 128 stores ----
    auto do_fill = [&]() {
        float* const wfill = out + (size_t)grow0 * SNN_ROW;
        const float4 z = make_float4(0.f, 0.f, 0.f, 0.f);
#pragma unroll 8
        for (int s = 0; s < 128; ++s) {
            const int fidx = (s << 6) + lane;
            const int rl   = fidx >> 11;          // 2048 float4 per row
            const int c4   = fidx & 2047;
            *reinterpret_cast<float4*>(wfill + rl * SNN_ROW + SNN_N + (c4 << 2)) = z;
        }
    };

    // ---------- GEMM: 4 rows x 4 cols per thread, load-only vmcnt queue ----
    auto do_gemm = [&]() {
        const float4* wt4 = reinterpret_cast<const float4*>(WT);   // [k][64 f4]
        const float4* xs4 = reinterpret_cast<const float4*>(&xs[0][0]);
        const int xbase = wave * 4 * 64;

        float acc[4][4];
#pragma unroll
        for (int r = 0; r < 4; ++r)
#pragma unroll
            for (int c = 0; c < 4; ++c) acc[r][c] = 0.0f;

        float4 wcur0 = wt4[0 * 64 + lane];
        float4 wcur1 = wt4[1 * 64 + lane];
        float4 wcur2 = wt4[2 * 64 + lane];
        float4 wcur3 = wt4[3 * 64 + lane];
        float4 xcur[4];
#pragma unroll
        for (int r = 0; r < 4; ++r) xcur[r] = xs4[xbase + r * 64 + 0];

        for (int i = 0; i < 64; ++i) {
            const int ip = (i + 1) & 63;
            float4 wnx0 = wt4[(ip * 4 + 0) * 64 + lane];
            float4 wnx1 = wt4[(ip * 4 + 1) * 64 + lane];
            float4 wnx2 = wt4[(ip * 4 + 2) * 64 + lane];
            float4 wnx3 = wt4[(ip * 4 + 3) * 64 + lane];
            float4 xnxt[4];
#pragma unroll
            for (int r = 0; r < 4; ++r) xnxt[r] = xs4[xbase + r * 64 + ip];

#pragma unroll
            for (int r = 0; r < 4; ++r) {
                const float4 xr = xcur[r];
                acc[r][0] = fmaf(xr.x, wcur0.x, acc[r][0]);
                acc[r][1] = fmaf(xr.x, wcur0.y, acc[r][1]);
                acc[r][2] = fmaf(xr.x, wcur0.z, acc[r][2]);
                acc[r][3] = fmaf(xr.x, wcur0.w, acc[r][3]);
                acc[r][0] = fmaf(xr.y, wcur1.x, acc[r][0]);
                acc[r][1] = fmaf(xr.y, wcur1.y, acc[r][1]);
                acc[r][2] = fmaf(xr.y, wcur1.z, acc[r][2]);
                acc[r][3] = fmaf(xr.y, wcur1.w, acc[r][3]);
                acc[r][0] = fmaf(xr.z, wcur2.x, acc[r][0]);
                acc[r][1] = fmaf(xr.z, wcur2.y, acc[r][1]);
                acc[r][2] = fmaf(xr.z, wcur2.z, acc[r][2]);
                acc[r][3] = fmaf(xr.z, wcur2.w, acc[r][3]);
                acc[r][0] = fmaf(xr.w, wcur3.x, acc[r][0]);
                acc[r][1] = fmaf(xr.w, wcur3.y, acc[r][1]);
                acc[r][2] = fmaf(xr.w, wcur3.z, acc[r][2]);
                acc[r][3] = fmaf(xr.w, wcur3.w, acc[r][3]);
            }

            wcur0 = wnx0; wcur1 = wnx1; wcur2 = wnx2; wcur3 = wnx3;
#pragma unroll
            for (int r = 0; r < 4; ++r) xcur[r] = xnxt[r];
        }

        const float4 bb = reinterpret_cast<const float4*>(bias)[lane];
#pragma unroll
        for (int r = 0; r < 4; ++r) {
            float h[4] = {acc[r][0] + bb.x, acc[r][1] + bb.y,
                          acc[r][2] + bb.z, acc[r][3] + bb.w};
            float s[4];
#pragma unroll
            for (int c = 0; c < 4; ++c) {
                if (__builtin_expect(fabsf(h[c] - 1.0f) < 1e-3f, 0)) {
                    // Borderline (f32 accum err <= ~6e-5 << 1e-3): f64 recheck.
                    const int n = 4 * lane + c;
                    double a = (double)bias[n];
                    const float* wr = W + (size_t)n * SNN_N;
                    for (int k = 0; k < SNN_N; ++k)
                        a += (double)wr[k] * (double)xs[wave * 4 + r][k];
                    s[c] = (a > 1.0) ? 1.0f : 0.0f;
                } else {
                    s[c] = (h[c] > 1.0f) ? 1.0f : 0.0f;
                }
            }
            *reinterpret_cast<float4*>(out + (size_t)(grow0 + r) * SNN_ROW + (lane << 2))
                = make_float4(s[0], s[1], s[2], s[3]);
        }
    };

    if (phase) { do_fill(); do_gemm(); }
    else       { do_gemm(); do_fill(); }
}

// ---- Fallback (ws too small): round-2 monolithic kernel (69 us, absmax 0) ----
__global__ __launch_bounds__(256) void polysnn_mono_kernel(
    const float* __restrict__ x, const float* __restrict__ W,
    const float* __restrict__ bias, float* __restrict__ out)
{
    __shared__ float xs[8][SNN_N];
    const int tid = threadIdx.x;
    const int row0 = blockIdx.x * 8;
    {
        const float4* x4  = reinterpret_cast<const float4*>(x + (size_t)row0 * SNN_N);
        float4*       xsw = reinterpret_cast<float4*>(&xs[0][0]);
        xsw[tid] = x4[tid]; xsw[tid + 256] = x4[tid + 256];
    }
    __syncthreads();
    const float4 zz = make_float4(0.f, 0.f, 0.f, 0.f);
#pragma unroll
    for (int r = 0; r < 8; ++r) {
        float4* o4 = reinterpret_cast<float4*>(out + (size_t)(row0 + r) * SNN_ROW + SNN_N);
#pragma unroll
        for (int i = 0; i < 8; ++i) o4[tid + i * 256] = zz;
    }
    const int n = tid;
    float acc[8];
#pragma unroll
    for (int r = 0; r < 8; ++r) acc[r] = 0.0f;
    const float4* w4  = reinterpret_cast<const float4*>(W + (size_t)n * SNN_N);
    const float4* xs4 = reinterpret_cast<const float4*>(&xs[0][0]);
#pragma unroll 4
    for (int k4 = 0; k4 < SNN_N / 4; ++k4) {
        const float4 w = w4[k4];
#pragma unroll
        for (int r = 0; r < 8; ++r) {
            const float4 xr = xs4[r * 64 + k4];
            acc[r] = fmaf(w.x, xr.x, acc[r]); acc[r] = fmaf(w.y, xr.y, acc[r]);
            acc[r] = fmaf(w.z, xr.z, acc[r]); acc[r] = fmaf(w.w, xr.w, acc[r]);
        }
    }
    const float bn = bias[n];
#pragma unroll
    for (int r = 0; r < 8; ++r) {
        const float h = acc[r] + bn;
        float spike;
        if (__builtin_expect(fabsf(h - 1.0f) < 1e-3f, 0)) {
            double a = (double)bn;
            const float* wr = W + (size_t)n * SNN_N;
            for (int k = 0; k < SNN_N; ++k) a += (double)wr[k] * (double)xs[r][k];
            spike = (a > 1.0) ? 1.0f : 0.0f;
        } else spike = (h > 1.0f) ? 1.0f : 0.0f;
        out[(size_t)(row0 + r) * SNN_ROW + n] = spike;
    }
}

extern "C" void kernel_launch(void* const* d_in, const int* in_sizes, int n_in,
                              void* d_out, int out_size, void* d_ws, size_t ws_size,
                              hipStream_t stream) {
    const float* x     = (const float*)d_in[0];
    const float* W_lin = (const float*)d_in[1];
    const float* b_lin = (const float*)d_in[2];
    // d_in[3] (W_sel) and d_in[4] (b_sel) are dead: spk_mode == 0 identically.
    float* out = (float*)d_out;

    if (ws_size >= (size_t)SNN_N * SNN_N * sizeof(float)) {
        float* WT = (float*)d_ws;
        w_transpose_kernel<<<256, 256, 0, stream>>>(W_lin, WT);
        polysnn_main_kernel<<<SNN_B / BLK_ROWS, 256, 0, stream>>>(x, W_lin, WT, b_lin, out);
    } else {
        polysnn_mono_kernel<<<SNN_B / 8, 256, 0, stream>>>(x, W_lin, b_lin, out);
    }
}